// Round 5
// baseline (5067.121 us; speedup 1.0000x reference)
//
#include <hip/hip_runtime.h>

#define N_  384
#define C_  128
#define NN_ (N_*N_)

// ---------------------------------------------------------------------------
// N1: one pair-row per block (128 threads). Computes both LNs in f32, then
// four 128-dot projections split across thread quarters:
//   q0: LN_l @ W_l   q1: pair @ W_e (+q0 -> left)   q2: gate   q3: right
// Stores bf16 planes for h in [h0, h0+32).
// rightC is stored transposed: [h_local][j*384 + k] (B^T layout for einsum).
// ---------------------------------------------------------------------------
__global__ __launch_bounds__(128) void n_proj(
    const float* __restrict__ pair,
    const float* __restrict__ gl,  const float* __restrict__ bl,
    const float* __restrict__ gr,  const float* __restrict__ br,
    const float* __restrict__ Wl,  const float* __restrict__ bsl,
    const float* __restrict__ Wr,  const float* __restrict__ bsr,
    const float* __restrict__ Wg,  const float* __restrict__ bsg,
    const float* __restrict__ We,  const float* __restrict__ bse,
    int h0,
    __bf16* __restrict__ leftC, __bf16* __restrict__ rightC,
    __bf16* __restrict__ gateC)
{
    __shared__ float xs[128], lnl[128], lnr[128], red[128], tmpL[32];
    const int t = threadIdx.x;
    const int rid = blockIdx.x;

    float x = pair[(size_t)rid*C_ + t];
    xs[t] = x;
    red[t] = x;
    __syncthreads();
    for (int s = 64; s > 0; s >>= 1) { if (t < s) red[t] += red[t+s]; __syncthreads(); }
    float m = red[0] * (1.f/128.f);
    __syncthreads();
    red[t] = x*x;
    __syncthreads();
    for (int s = 64; s > 0; s >>= 1) { if (t < s) red[t] += red[t+s]; __syncthreads(); }
    float v = red[0] * (1.f/128.f) - m*m;
    float rs = rsqrtf(v + 1e-5f);
    lnl[t] = (x - m)*rs*gl[t] + bl[t];
    lnr[t] = (x - m)*rs*gr[t] + br[t];
    __syncthreads();

    const int q = t >> 5, hh = t & 31, h = h0 + hh;
    float acc = 0.f;
    if (q == 0) {
        for (int c = 0; c < 128; ++c) acc += lnl[c] * Wl[c*C_ + h];
        tmpL[hh] = acc;
    }
    __syncthreads();
    if (q == 1) {
        for (int c = 0; c < 128; ++c) acc += xs[c] * We[c*C_ + h];
        float left = tmpL[hh] + acc + bsl[h] + bse[h];
        leftC[(size_t)hh*NN_ + rid] = (__bf16)left;
    } else if (q == 2) {
        for (int c = 0; c < 128; ++c) acc += xs[c] * Wg[c*C_ + h];
        float g = 1.f / (1.f + expf(-(acc + bsg[h])));
        gateC[(size_t)hh*NN_ + rid] = (__bf16)g;
    } else if (q == 3) {
        for (int c = 0; c < 128; ++c) acc += lnr[c] * Wr[c*C_ + h];
        float r = acc + bsr[h];
        // rid = k*384 + j  ->  store at [j*384 + k]
        rightC[(size_t)hh*NN_ + (size_t)(rid % N_)*N_ + (rid / N_)] = (__bf16)r;
    }
}

// ---------------------------------------------------------------------------
// N2: einsum + gate for one h-chunk. Block = (h_local, j, i-chunk of 128).
//   out[i,j,h] = sum_k leftC[h][i*384+k] * rightC[h][j*384+k]
// Written as outG[h][j*384 + i] (bf16).
// ---------------------------------------------------------------------------
__global__ __launch_bounds__(128) void n_einsum(
    const __bf16* __restrict__ leftC, const __bf16* __restrict__ rightC,
    const __bf16* __restrict__ gateC, __bf16* __restrict__ outG, int h0)
{
    __shared__ float rsh[384];
    const int t = threadIdx.x;
    int bid = blockIdx.x;
    const int ic = bid % 3;  bid /= 3;
    const int j  = bid % N_; bid /= N_;
    const int hl = bid;                         // 0..31
    const size_t hNN = (size_t)hl * NN_;

    for (int kk = t; kk < N_; kk += 128)
        rsh[kk] = (float)rightC[hNN + (size_t)j*N_ + kk];
    __syncthreads();

    const int i = ic*128 + t;
    const __bf16* lrow = leftC + hNN + (size_t)i*N_;
    float acc = 0.f;
    for (int k = 0; k < N_; ++k) acc += (float)lrow[k] * rsh[k];
    float g = (float)gateC[hNN + (size_t)i*N_ + j];
    outG[(size_t)(h0+hl)*NN_ + (size_t)j*N_ + i] = (__bf16)(acc * g);
}

// ---------------------------------------------------------------------------
// N3: out2 = gated_einsum @ W_o + bias_o; z = out2 + pair; LN_out(z).
// One output row (i,j) per block, thread = channel c. f32 in/out.
// ---------------------------------------------------------------------------
__global__ __launch_bounds__(128) void n_out(
    const __bf16* __restrict__ outG, const float* __restrict__ Wo,
    const float* __restrict__ bso,  const float* __restrict__ pair,
    const float* __restrict__ go,   const float* __restrict__ bo,
    float* __restrict__ out)
{
    __shared__ float red[128];
    __shared__ float oh[128];
    const int t = threadIdx.x;
    const int rid = blockIdx.x;
    const int i = rid / N_, j = rid % N_;

    oh[t] = (float)outG[(size_t)t*NN_ + (size_t)j*N_ + i];
    __syncthreads();

    float acc = 0.f;
    for (int h = 0; h < 128; ++h) acc += oh[h] * Wo[h*C_ + t];
    float z = acc + bso[t] + pair[(size_t)rid*C_ + t];

    red[t] = z;
    __syncthreads();
    for (int s = 64; s > 0; s >>= 1) { if (t < s) red[t] += red[t+s]; __syncthreads(); }
    float m = red[0] * (1.f/128.f);
    __syncthreads();
    red[t] = z*z;
    __syncthreads();
    for (int s = 64; s > 0; s >>= 1) { if (t < s) red[t] += red[t+s]; __syncthreads(); }
    float v = red[0] * (1.f/128.f) - m*m;
    float rsq = rsqrtf(v + 1e-5f);

    out[(size_t)rid*C_ + t] = (z - m)*rsq*go[t] + bo[t];
}

// ---------------------------------------------------------------------------
extern "C" void kernel_launch(void* const* d_in, const int* in_sizes, int n_in,
                              void* d_out, int out_size, void* d_ws, size_t ws_size,
                              hipStream_t stream)
{
    const float* pair    = (const float*)d_in[0];
    const float* g_left  = (const float*)d_in[1];
    const float* b_left  = (const float*)d_in[2];
    const float* g_right = (const float*)d_in[3];
    const float* b_right = (const float*)d_in[4];
    const float* g_out   = (const float*)d_in[5];
    const float* b_out   = (const float*)d_in[6];
    const float* W_l     = (const float*)d_in[7];
    const float* bias_l  = (const float*)d_in[8];
    const float* W_r     = (const float*)d_in[9];
    const float* bias_r  = (const float*)d_in[10];
    const float* W_g     = (const float*)d_in[11];
    const float* bias_g  = (const float*)d_in[12];
    const float* W_e     = (const float*)d_in[13];
    const float* bias_e  = (const float*)d_in[14];
    const float* W_o     = (const float*)d_in[15];
    const float* bias_o  = (const float*)d_in[16];

    // ws: outG only (128 bf16 planes = 37.75 MB) — minimal ws dependence.
    // d_out hosts the per-chunk transients: left/right/gate (32 planes each,
    // 28.3 MB of 75.5 MB); all dead before n_out overwrites d_out.
    __bf16* outG   = (__bf16*)d_ws;
    __bf16* leftC  = (__bf16*)d_out;
    __bf16* rightC = leftC + (size_t)32*NN_;
    __bf16* gateC  = leftC + (size_t)64*NN_;

    for (int h0 = 0; h0 < 128; h0 += 32) {
        n_proj<<<NN_, 128, 0, stream>>>(pair,
            g_left, b_left, g_right, b_right,
            W_l, bias_l, W_r, bias_r, W_g, bias_g, W_e, bias_e,
            h0, leftC, rightC, gateC);
        n_einsum<<<32*N_*3, 128, 0, stream>>>(leftC, rightC, gateC, outG, h0);
    }
    n_out<<<NN_, 128, 0, stream>>>(outG, W_o, bias_o, pair, g_out, b_out,
                                   (float*)d_out);
}

// Round 8
// 3111.966 us; speedup vs baseline: 1.6283x; 1.6283x over previous
//
#include <hip/hip_runtime.h>

#define N_  384
#define C_  128
#define NN_ (N_*N_)

typedef __bf16 bf16x8 __attribute__((ext_vector_type(8)));
typedef float  floatx4 __attribute__((ext_vector_type(4)));

__device__ inline unsigned short f2bf(float f) {
    __bf16 h = (__bf16)f;
    return __builtin_bit_cast(unsigned short, h);
}

// ---------------------------------------------------------------------------
// N1 (PROVEN round 5): one pair-row per block (128 threads).
// ---------------------------------------------------------------------------
__global__ __launch_bounds__(128) void n_proj(
    const float* __restrict__ pair,
    const float* __restrict__ gl,  const float* __restrict__ bl,
    const float* __restrict__ gr,  const float* __restrict__ br,
    const float* __restrict__ Wl,  const float* __restrict__ bsl,
    const float* __restrict__ Wr,  const float* __restrict__ bsr,
    const float* __restrict__ Wg,  const float* __restrict__ bsg,
    const float* __restrict__ We,  const float* __restrict__ bse,
    int h0,
    __bf16* __restrict__ leftC, __bf16* __restrict__ rightC,
    __bf16* __restrict__ gateC)
{
    __shared__ float xs[128], lnl[128], lnr[128], red[128], tmpL[32];
    const int t = threadIdx.x;
    const int rid = blockIdx.x;

    float x = pair[(size_t)rid*C_ + t];
    xs[t] = x;
    red[t] = x;
    __syncthreads();
    for (int s = 64; s > 0; s >>= 1) { if (t < s) red[t] += red[t+s]; __syncthreads(); }
    float m = red[0] * (1.f/128.f);
    __syncthreads();
    red[t] = x*x;
    __syncthreads();
    for (int s = 64; s > 0; s >>= 1) { if (t < s) red[t] += red[t+s]; __syncthreads(); }
    float v = red[0] * (1.f/128.f) - m*m;
    float rs = rsqrtf(v + 1e-5f);
    lnl[t] = (x - m)*rs*gl[t] + bl[t];
    lnr[t] = (x - m)*rs*gr[t] + br[t];
    __syncthreads();

    const int q = t >> 5, hh = t & 31, h = h0 + hh;
    float acc = 0.f;
    if (q == 0) {
        for (int c = 0; c < 128; ++c) acc += lnl[c] * Wl[c*C_ + h];
        tmpL[hh] = acc;
    }
    __syncthreads();
    if (q == 1) {
        for (int c = 0; c < 128; ++c) acc += xs[c] * We[c*C_ + h];
        float left = tmpL[hh] + acc + bsl[h] + bse[h];
        leftC[(size_t)hh*NN_ + rid] = (__bf16)left;
    } else if (q == 2) {
        for (int c = 0; c < 128; ++c) acc += xs[c] * Wg[c*C_ + h];
        float g = 1.f / (1.f + expf(-(acc + bsg[h])));
        gateC[(size_t)hh*NN_ + rid] = (__bf16)g;
    } else if (q == 3) {
        for (int c = 0; c < 128; ++c) acc += lnr[c] * Wr[c*C_ + h];
        float r = acc + bsr[h];
        rightC[(size_t)hh*NN_ + (size_t)(rid % N_)*N_ + (rid / N_)] = (__bf16)r;
    }
}

// ---------------------------------------------------------------------------
// UNDER TEST: MFMA einsum with in-kernel C/D-orientation probe.
// grid = 32 * 9 per h-chunk.
// ---------------------------------------------------------------------------
__global__ __launch_bounds__(256) void k_einsum(
    const __bf16* __restrict__ leftC, const __bf16* __restrict__ rightC,
    const __bf16* __restrict__ gate, __bf16* __restrict__ outG)
{
    __shared__ __align__(16) __bf16 sA[128][32];
    __shared__ __align__(16) __bf16 sB[128][32];
    __shared__ __align__(16) __bf16 sGate[128][136];

    const int bid = blockIdx.x;
    const int hl = bid / 9, t9 = bid % 9;
    const int ti = (t9 / 3) * 128, tj = (t9 % 3) * 128;
    const int tid = threadIdx.x, lane = tid & 63, w = tid >> 6;
    const int l15 = lane & 15, quad = lane >> 4;
    const size_t hNN = (size_t)hl * NN_;

    const int ar = (lane >> 2);
    const int ac = (lane & 3) * 8;
    const __bf16* gA = leftC  + hNN + (size_t)ti * N_;
    const __bf16* gB = rightC + hNN + (size_t)tj * N_;

    floatx4 acc[4][4] = {};

    for (int ks = 0; ks < 12; ++ks) {
        const int kc = ks * 32;
        uint4 va[2], vb[2];
        #pragma unroll
        for (int it = 0; it < 2; ++it) {
            int row = w*32 + it*16 + ar;
            va[it] = *(const uint4*)(gA + (size_t)row*N_ + kc + ac);
            vb[it] = *(const uint4*)(gB + (size_t)row*N_ + kc + ac);
        }
        #pragma unroll
        for (int it = 0; it < 2; ++it) {
            int row = w*32 + it*16 + ar;
            *(uint4*)&sA[row][ac] = va[it];
            *(uint4*)&sB[row][ac] = vb[it];
        }
        __syncthreads();
        bf16x8 af[4], bfr[4];
        #pragma unroll
        for (int mt = 0; mt < 4; ++mt)
            af[mt] = *(const bf16x8*)&sA[(w&1)*64 + mt*16 + l15][quad*8];
        #pragma unroll
        for (int nt = 0; nt < 4; ++nt)
            bfr[nt] = *(const bf16x8*)&sB[(w>>1)*64 + nt*16 + l15][quad*8];
        #pragma unroll
        for (int mt = 0; mt < 4; ++mt)
            #pragma unroll
            for (int nt = 0; nt < 4; ++nt)
                acc[mt][nt] = __builtin_amdgcn_mfma_f32_16x16x32_bf16(af[mt], bfr[nt], acc[mt][nt], 0, 0, 0);
        __syncthreads();
    }

    // stage gate tile gate[i][j] (plane layout rid = i*384+j)
    #pragma unroll
    for (int it = 0; it < 8; ++it) {
        int cid = it*256 + tid;
        int ri = cid >> 4, c8 = cid & 15;
        *(uint4*)&sGate[ri][c8*8] =
            *(const uint4*)(gate + hNN + (size_t)(ti + ri)*N_ + tj + c8*8);
    }
    __syncthreads();

    // ---- in-register C/D orientation probe ----
    // Per assumed operand layouts (m/n = lane&15, k = quad*8+j):
    //   A=1 at (m=1,k=0);  B^T=1 at (n=2,k=0)  =>  D=1 at (m=1,n=2).
    bf16x8 pa = {}; bf16x8 pb = {};
    if (lane == 1) pa[0] = (__bf16)1.0f;
    if (lane == 2) pb[0] = (__bf16)1.0f;
    floatx4 pd = {};
    pd = __builtin_amdgcn_mfma_f32_16x16x32_bf16(pa, pb, pd, 0, 0, 0);
    // H1 (row=quad*4+reg is m, col=lane&15 is n): 1 at lane 2 (s=2,q=0), reg 1.
    // H2 (transposed):                            1 at lane 1 (s=1,q=0), reg 2.
    float h1v = __shfl(pd[1], 2, 64);
    float h2v = __shfl(pd[2], 1, 64);
    const bool H1 = (h1v > 0.5f) && !(h2v > 0.5f);
    const bool H2 = (h2v > 0.5f) && !(h1v > 0.5f);

    const int ib = (w & 1) * 64, jbw = (w >> 1) * 64;
    if (H1) {
        #pragma unroll
        for (int mt = 0; mt < 4; ++mt) {
            const int i_base = ib + mt*16 + quad*4;
            #pragma unroll
            for (int nt = 0; nt < 4; ++nt) {
                const int j_loc = jbw + nt*16 + l15;
                union { unsigned short us[4]; uint2 v; } p;
                #pragma unroll
                for (int rr = 0; rr < 4; ++rr) {
                    float g = (float)sGate[i_base + rr][j_loc];
                    p.us[rr] = f2bf(acc[mt][nt][rr] * g);
                }
                *(uint2*)(outG + hNN + (size_t)(tj + j_loc)*N_ + ti + i_base) = p.v;
            }
        }
    } else if (H2) {
        #pragma unroll
        for (int mt = 0; mt < 4; ++mt) {
            const int i_loc = ib + mt*16 + l15;
            #pragma unroll
            for (int nt = 0; nt < 4; ++nt) {
                #pragma unroll
                for (int rr = 0; rr < 4; ++rr) {
                    const int j_loc = jbw + nt*16 + quad*4 + rr;
                    float g = (float)sGate[i_loc][j_loc];
                    outG[hNN + (size_t)(tj + j_loc)*N_ + ti + i_loc] =
                        (__bf16)(acc[mt][nt][rr] * g);
                }
            }
        }
    } else {
        // neither orientation matched: write sentinel for diagnosis
        #pragma unroll
        for (int mt = 0; mt < 4; ++mt) {
            const int i_base = ib + mt*16 + quad*4;
            #pragma unroll
            for (int nt = 0; nt < 4; ++nt) {
                const int j_loc = jbw + nt*16 + l15;
                #pragma unroll
                for (int rr = 0; rr < 4; ++rr)
                    outG[hNN + (size_t)(tj + j_loc)*N_ + ti + i_base + rr] =
                        (__bf16)1000.0f;
            }
        }
    }
}

// ---------------------------------------------------------------------------
// N3 (PROVEN round 5): output projection + residual + LN. f32 in/out.
// ---------------------------------------------------------------------------
__global__ __launch_bounds__(128) void n_out(
    const __bf16* __restrict__ outG, const float* __restrict__ Wo,
    const float* __restrict__ bso,  const float* __restrict__ pair,
    const float* __restrict__ go,   const float* __restrict__ bo,
    float* __restrict__ out)
{
    __shared__ float red[128];
    __shared__ float oh[128];
    const int t = threadIdx.x;
    const int rid = blockIdx.x;
    const int i = rid / N_, j = rid % N_;

    oh[t] = (float)outG[(size_t)t*NN_ + (size_t)j*N_ + i];
    __syncthreads();

    float acc = 0.f;
    for (int h = 0; h < 128; ++h) acc += oh[h] * Wo[h*C_ + t];
    float z = acc + bso[t] + pair[(size_t)rid*C_ + t];

    red[t] = z;
    __syncthreads();
    for (int s = 64; s > 0; s >>= 1) { if (t < s) red[t] += red[t+s]; __syncthreads(); }
    float m = red[0] * (1.f/128.f);
    __syncthreads();
    red[t] = z*z;
    __syncthreads();
    for (int s = 64; s > 0; s >>= 1) { if (t < s) red[t] += red[t+s]; __syncthreads(); }
    float v = red[0] * (1.f/128.f) - m*m;
    float rsq = rsqrtf(v + 1e-5f);

    out[(size_t)rid*C_ + t] = (z - m)*rsq*go[t] + bo[t];
}

// ---------------------------------------------------------------------------
extern "C" void kernel_launch(void* const* d_in, const int* in_sizes, int n_in,
                              void* d_out, int out_size, void* d_ws, size_t ws_size,
                              hipStream_t stream)
{
    const float* pair    = (const float*)d_in[0];
    const float* g_left  = (const float*)d_in[1];
    const float* b_left  = (const float*)d_in[2];
    const float* g_right = (const float*)d_in[3];
    const float* b_right = (const float*)d_in[4];
    const float* g_out   = (const float*)d_in[5];
    const float* b_out   = (const float*)d_in[6];
    const float* W_l     = (const float*)d_in[7];
    const float* bias_l  = (const float*)d_in[8];
    const float* W_r     = (const float*)d_in[9];
    const float* bias_r  = (const float*)d_in[10];
    const float* W_g     = (const float*)d_in[11];
    const float* bias_g  = (const float*)d_in[12];
    const float* W_e     = (const float*)d_in[13];
    const float* bias_e  = (const float*)d_in[14];
    const float* W_o     = (const float*)d_in[15];
    const float* bias_o  = (const float*)d_in[16];

    // ws: outG only (128 bf16 planes = 37.75MB, proven safe).
    // d_out hosts per-chunk transients (nH=32): left/right/gate = 28.3MB.
    __bf16* outG   = (__bf16*)d_ws;
    __bf16* leftC  = (__bf16*)d_out;
    __bf16* rightC = leftC + (size_t)32*NN_;
    __bf16* gateC  = leftC + (size_t)64*NN_;

    for (int h0 = 0; h0 < 128; h0 += 32) {
        n_proj<<<NN_, 128, 0, stream>>>(pair,
            g_left, b_left, g_right, b_right,
            W_l, bias_l, W_r, bias_r, W_g, bias_g, W_e, bias_e,
            h0, leftC, rightC, gateC);
        k_einsum<<<32*9, 256, 0, stream>>>(leftC, rightC, gateC,
                                           outG + (size_t)h0*NN_);
    }
    n_out<<<NN_, 128, 0, stream>>>(outG, W_o, bias_o, pair, g_out, b_out,
                                   (float*)d_out);
}